// Round 6
// baseline (449.719 us; speedup 1.0000x reference)
//
#include <hip/hip_runtime.h>
#include <cmath>

// INGP hashgrid encode — R11: sort + ONE fused kernel.
//   Validated model: gather bound by random L2 line-lookups (~4.4us/M);
//   Morton sort makes wave lanes spatially adjacent -> coarse/mid lookups
//   merge (R9: 203 -> 146.7us, quantitative match). But the two-kernel
//   structure burned the win: ws round-trip (64MB write + 64MB read) +
//   perm-scatter transpose + sort dispatches = 178us fixed overhead
//   (R9 == R10 residual, invariant under scatter packing).
//   R11 fuses all 16 levels into one kernel, one thread = one sorted point:
//   - acc[32] in registers (fully unrolled -> no scratch, rule #20);
//   - writes the point's WHOLE 128B out row (2 full 64B lines, single
//     owner) at its ORIGINAL index. R5's catastrophe was cross-XCD
//     SHARED-line scatter ([N][L] lines written 8B-wise by blocks on
//     different XCDs); single-owner full-line rows don't bounce.
//   - fine levels lose XCD-pinned L2 residency, but they have zero
//     inter-point reuse post-sort anyway (cells >> points); misses fall
//     through to the shared 256MB L3 where all 64MB of tables resides.
//   - coarse levels get locality from the sort (per-wave footprint ~KB ->
//     TA merge + L1).
//   Deleted: ws staging (128MB traffic), transpose dispatch, perm array,
//   16x redundant point reads.

constexpr int LVLS = 16;
constexpr unsigned TBL = 1u << 19;
constexpr unsigned TMASK = TBL - 1u;
constexpr unsigned P1 = 2654435761u;
constexpr unsigned P2 = 805459861u;
constexpr int NBINS = 32768;         // 32^3 Morton bins

typedef float vf2 __attribute__((ext_vector_type(2)));
typedef float vf4 __attribute__((ext_vector_type(4)));

struct ResArr { float r[LVLS]; };

__device__ __forceinline__ unsigned spread5(unsigned v) {
    v &= 31u;
    v = (v | (v << 8)) & 0x100Fu;
    v = (v | (v << 4)) & 0x10C3u;
    v = (v | (v << 2)) & 0x1249u;
    return v;
}

__device__ __forceinline__ unsigned bin_key(float px, float py, float pz) {
    float x = (px + 1.0f) * 0.5f;
    float y = (py + 1.0f) * 0.5f;
    float z = (pz + 1.0f) * 0.5f;
    unsigned bx = (unsigned)fminf(31.f, fmaxf(0.f, floorf(x * 32.f)));
    unsigned by = (unsigned)fminf(31.f, fmaxf(0.f, floorf(y * 32.f)));
    unsigned bz = (unsigned)fminf(31.f, fmaxf(0.f, floorf(z * 32.f)));
    return spread5(bx) | (spread5(by) << 1) | (spread5(bz) << 2);
}

__global__ __launch_bounds__(256) void ingp_hist(
    const float* __restrict__ pts, unsigned* __restrict__ hist, int npts)
{
    int i = blockIdx.x * 256 + threadIdx.x;
    if (i >= npts) return;
    float px = pts[i * 3 + 0], py = pts[i * 3 + 1], pz = pts[i * 3 + 2];
    atomicAdd(&hist[bin_key(px, py, pz)], 1u);
}

// Exclusive scan of 32768 bin counts, single block of 1024 threads.
__global__ __launch_bounds__(1024) void ingp_scan(
    const unsigned* __restrict__ hist, unsigned* __restrict__ offs)
{
    __shared__ unsigned sc[1024];
    int t = threadIdx.x;
    unsigned loc[32];
    unsigned s = 0;
    #pragma unroll
    for (int i = 0; i < 32; ++i) { loc[i] = s; s += hist[t * 32 + i]; }
    sc[t] = s;
    __syncthreads();
    for (int d = 1; d < 1024; d <<= 1) {
        unsigned v = (t >= d) ? sc[t - d] : 0u;
        __syncthreads();
        sc[t] += v;
        __syncthreads();
    }
    unsigned base = sc[t] - s;   // exclusive prefix of this thread's chunk
    #pragma unroll
    for (int i = 0; i < 32; ++i) offs[t * 32 + i] = base + loc[i];
}

// Packed scatter: one aligned 16B store per point {x,y,z,bits(orig idx)}.
__global__ __launch_bounds__(256) void ingp_scatter(
    const float* __restrict__ pts, unsigned* __restrict__ offs,
    vf4* __restrict__ pts4, int npts)
{
    int i = blockIdx.x * 256 + threadIdx.x;
    if (i >= npts) return;
    float px = pts[i * 3 + 0], py = pts[i * 3 + 1], pz = pts[i * 3 + 2];
    unsigned pos = atomicAdd(&offs[bin_key(px, py, pz)], 1u);
    vf4 o; o.x = px; o.y = py; o.z = pz; o.w = __int_as_float(i);
    pts4[pos] = o;
}

// One thread = one (sorted) point; all 16 levels in registers; one 128B
// single-owner output row at the original index.
template<bool SORTED>
__global__ __launch_bounds__(256) void ingp_fused(
    const float* __restrict__ pts,    // SORTED=false: raw [N][3]
    const vf4* __restrict__ pts4,     // SORTED=true: [N] {x,y,z,idx}
    const float* __restrict__ tables,
    vf4* __restrict__ out,            // [N][8] vf4 = [N][L] float2
    ResArr ra, int npts)
{
    int i = blockIdx.x * 256 + threadIdx.x;
    bool valid = i < npts;
    int pp = valid ? i : 0;
    float px, py, pz; int orig;
    if (SORTED) {
        vf4 v = __builtin_nontemporal_load(pts4 + pp);
        px = v.x; py = v.y; pz = v.z; orig = __float_as_int(v.w);
    } else {
        px = pts[pp * 3 + 0];
        py = pts[pp * 3 + 1];
        pz = pts[pp * 3 + 2];
        orig = pp;
    }
    float x = (px + 1.0f) * 0.5f;
    float y = (py + 1.0f) * 0.5f;
    float z = (pz + 1.0f) * 0.5f;

    float acc[2 * LVLS];   // fully unrolled -> stays in VGPRs (rule #20)

    #pragma unroll
    for (int l = 0; l < LVLS; ++l) {
        float r = ra.r[l];
        const float2* __restrict__ tab = (const float2*)tables + (size_t)l * TBL;

        float posx = x * r, posy = y * r, posz = z * r;
        float fx = floorf(posx), fy = floorf(posy), fz = floorf(posz);
        float wx = posx - fx, wy = posy - fy, wz = posz - fz;
        unsigned ix = (unsigned)fx, iy = (unsigned)fy, iz = (unsigned)fz;
        unsigned hx0 = ix,      hx1 = ix + 1u;
        unsigned hy0 = iy * P1;
        unsigned hz0 = iz * P2, hz1 = hz0 + P2;

        unsigned hyz[4];
        hyz[0] = hy0 ^ hz0;
        hyz[1] = hy0 ^ hz1;
        hyz[2] = (hy0 + P1) ^ hz0;
        hyz[3] = (hy0 + P1) ^ hz1;

        // v[i*4+yz]: corner (i,j,k)
        float2 v[8];
        if ((ix & 1u) == 0u) {
            // x-pair idx differ by ^1 -> one aligned float4 covers both.
            #pragma unroll
            for (int yz = 0; yz < 4; ++yz) {
                unsigned b0 = (hx0 ^ hyz[yz]) & TMASK;   // x=0 corner
                const vf4* lp4 = (const vf4*)(tab + (b0 & ~1u));
                vf4 qd = *lp4;
                float2 lo = make_float2(qd.x, qd.y);
                float2 hi = make_float2(qd.z, qd.w);
                bool odd = (b0 & 1u) != 0u;
                v[yz]     = odd ? hi : lo;   // x=0 corner
                v[4 + yz] = odd ? lo : hi;   // x=1 corner (idx = b0^1)
            }
        } else {
            #pragma unroll
            for (int yz = 0; yz < 4; ++yz) {
                unsigned b0 = (hx0 ^ hyz[yz]) & TMASK;
                unsigned b1 = (hx1 ^ hyz[yz]) & TMASK;
                v[yz]     = tab[b0];
                v[4 + yz] = tab[b1];
            }
        }

        float ox = 1.0f - wx, oy = 1.0f - wy, oz = 1.0f - wz;
        float w[8];
        w[0] = (ox * oy) * oz;   // (0,0,0)
        w[1] = (ox * oy) * wz;   // (0,0,1)
        w[2] = (ox * wy) * oz;   // (0,1,0)
        w[3] = (ox * wy) * wz;   // (0,1,1)
        w[4] = (wx * oy) * oz;   // (1,0,0)
        w[5] = (wx * oy) * wz;   // (1,0,1)
        w[6] = (wx * wy) * oz;   // (1,1,0)
        w[7] = (wx * wy) * wz;   // (1,1,1)

        float f0 = w[0] * v[0].x;
        float f1 = w[0] * v[0].y;
        #pragma unroll
        for (int c = 1; c < 8; ++c) {
            f0 += w[c] * v[c].x;
            f1 += w[c] * v[c].y;
        }
        acc[2 * l]     = f0;
        acc[2 * l + 1] = f1;
    }

    if (valid) {
        vf4* row = out + (size_t)orig * 8;   // 128B row, single owner
        #pragma unroll
        for (int k = 0; k < 8; ++k) {
            vf4 o;
            o.x = acc[4 * k + 0]; o.y = acc[4 * k + 1];
            o.z = acc[4 * k + 2]; o.w = acc[4 * k + 3];
            __builtin_nontemporal_store(o, row + k);
        }
    }
}

extern "C" void kernel_launch(void* const* d_in, const int* in_sizes, int n_in,
                              void* d_out, int out_size, void* d_ws, size_t ws_size,
                              hipStream_t stream) {
    const float* pts    = (const float*)d_in[0];
    const float* tables = (const float*)d_in[1];
    int npts = in_sizes[0] / 3;

    // numpy-bitwise RES: GROWTH = exp((log(2048)-log(16))/15); floor(16*G**l)
    ResArr ra;
    double growth = exp((log(2048.0) - log(16.0)) / 15.0);
    for (int l = 0; l < LVLS; ++l)
        ra.r[l] = (float)floor(16.0 * pow(growth, (double)l));

    int pgrid = (npts + 255) / 256;

    // ws layout: [hist: NBINS u32][offs: NBINS u32][pts4: N vf4]
    size_t sort_bytes = 2ull * NBINS * sizeof(unsigned) + (size_t)npts * sizeof(vf4);
    bool use_sort = ws_size >= sort_bytes;

    if (use_sort) {
        unsigned* hist = (unsigned*)d_ws;
        unsigned* offs = hist + NBINS;
        vf4*      pts4 = (vf4*)((char*)d_ws + 2ull * NBINS * sizeof(unsigned));

        hipMemsetAsync(hist, 0, NBINS * sizeof(unsigned), stream);
        hipLaunchKernelGGL(ingp_hist, dim3(pgrid), dim3(256), 0, stream,
                           pts, hist, npts);
        hipLaunchKernelGGL(ingp_scan, dim3(1), dim3(1024), 0, stream,
                           hist, offs);
        hipLaunchKernelGGL(ingp_scatter, dim3(pgrid), dim3(256), 0, stream,
                           pts, offs, pts4, npts);
        hipLaunchKernelGGL((ingp_fused<true>), dim3(pgrid), dim3(256), 0, stream,
                           nullptr, pts4, tables, (vf4*)d_out, ra, npts);
    } else {
        hipLaunchKernelGGL((ingp_fused<false>), dim3(pgrid), dim3(256), 0, stream,
                           pts, nullptr, tables, (vf4*)d_out, ra, npts);
    }
}

// Round 7
// 311.214 us; speedup vs baseline: 1.4450x; 1.4450x over previous
//
#include <hip/hip_runtime.h>
#include <cmath>

// INGP hashgrid encode — R12: sort + split-fused (pinned fine / fused coarse).
//   Validated: (R9) Morton sort -> wave-spatial locality -> coarse/mid corner
//   lookups merge in TA/L1: 16-level gather 203 -> 146.7us. (R11-neg) fine
//   levels MUST stay XCD-pinned: unpinned 16-table working set thrashes L2
//   (FETCH 130 -> 738MB, 316us). (R11-neg) per-thread 8x16B row stores
//   amplify writes 3.3x (partial-line in time); (R9-pos) 8-lanes-per-row
//   LDS-transpose stores are full-line clean (WRITE == output bytes).
//   Structure:
//     sort chain (memset/hist/scan/scatter, packed 16B pts4)
//     A ingp_fine:  levels 8-15, level-major XCD-pinned (lvl = 8 + b&7),
//                   tables L2-resident, writes ws[8][N] coalesced (32MB).
//     B ingp_finish: thread = sorted point; levels 0-7 in registers
//                   (sorted locality, no pinning needed); reads fine rows
//                   from ws coalesced; LDS-assembles; writes full 128B
//                   single-owner rows at ORIGINAL index via the proven
//                   8-lane/row full-line store pattern.
//   Deleted vs R9/R10: transpose dispatch, perm array, half the ws traffic.

constexpr int LVLS = 16;
constexpr unsigned TBL = 1u << 19;
constexpr unsigned TMASK = TBL - 1u;
constexpr unsigned P1 = 2654435761u;
constexpr unsigned P2 = 805459861u;
constexpr int PTS_PER_BLOCK = 512;   // fine kernel: 256 threads x 2 points
constexpr int NBINS = 32768;         // 32^3 Morton bins

typedef float vf2 __attribute__((ext_vector_type(2)));
typedef float vf4 __attribute__((ext_vector_type(4)));

struct ResArr { float r[LVLS]; };

__device__ __forceinline__ unsigned spread5(unsigned v) {
    v &= 31u;
    v = (v | (v << 8)) & 0x100Fu;
    v = (v | (v << 4)) & 0x10C3u;
    v = (v | (v << 2)) & 0x1249u;
    return v;
}

__device__ __forceinline__ unsigned bin_key(float px, float py, float pz) {
    float x = (px + 1.0f) * 0.5f;
    float y = (py + 1.0f) * 0.5f;
    float z = (pz + 1.0f) * 0.5f;
    unsigned bx = (unsigned)fminf(31.f, fmaxf(0.f, floorf(x * 32.f)));
    unsigned by = (unsigned)fminf(31.f, fmaxf(0.f, floorf(y * 32.f)));
    unsigned bz = (unsigned)fminf(31.f, fmaxf(0.f, floorf(z * 32.f)));
    return spread5(bx) | (spread5(by) << 1) | (spread5(bz) << 2);
}

// One level's trilinear hashed gather for normalized point (x,y,z).
__device__ __forceinline__ void level_gather(
    const float2* __restrict__ tab, float r,
    float x, float y, float z, float& f0, float& f1)
{
    float posx = x * r, posy = y * r, posz = z * r;
    float fx = floorf(posx), fy = floorf(posy), fz = floorf(posz);
    float wx = posx - fx, wy = posy - fy, wz = posz - fz;
    unsigned ix = (unsigned)fx, iy = (unsigned)fy, iz = (unsigned)fz;
    unsigned hx0 = ix, hx1 = ix + 1u;
    unsigned hy0 = iy * P1;
    unsigned hz0 = iz * P2, hz1 = hz0 + P2;

    unsigned hyz[4];
    hyz[0] = hy0 ^ hz0;
    hyz[1] = hy0 ^ hz1;
    hyz[2] = (hy0 + P1) ^ hz0;
    hyz[3] = (hy0 + P1) ^ hz1;

    // v[i*4+yz]: corner (i,j,k)
    float2 v[8];
    if ((ix & 1u) == 0u) {
        // x-pair idx differ by ^1 -> one aligned float4 covers both.
        #pragma unroll
        for (int yz = 0; yz < 4; ++yz) {
            unsigned b0 = (hx0 ^ hyz[yz]) & TMASK;   // x=0 corner
            vf4 qd = *(const vf4*)(tab + (b0 & ~1u));
            float2 lo = make_float2(qd.x, qd.y);
            float2 hi = make_float2(qd.z, qd.w);
            bool odd = (b0 & 1u) != 0u;
            v[yz]     = odd ? hi : lo;   // x=0 corner
            v[4 + yz] = odd ? lo : hi;   // x=1 corner (idx = b0^1)
        }
    } else {
        #pragma unroll
        for (int yz = 0; yz < 4; ++yz) {
            unsigned b0 = (hx0 ^ hyz[yz]) & TMASK;
            unsigned b1 = (hx1 ^ hyz[yz]) & TMASK;
            v[yz]     = tab[b0];
            v[4 + yz] = tab[b1];
        }
    }

    float ox = 1.0f - wx, oy = 1.0f - wy, oz = 1.0f - wz;
    float w[8];
    w[0] = (ox * oy) * oz;
    w[1] = (ox * oy) * wz;
    w[2] = (ox * wy) * oz;
    w[3] = (ox * wy) * wz;
    w[4] = (wx * oy) * oz;
    w[5] = (wx * oy) * wz;
    w[6] = (wx * wy) * oz;
    w[7] = (wx * wy) * wz;

    f0 = w[0] * v[0].x;
    f1 = w[0] * v[0].y;
    #pragma unroll
    for (int c = 1; c < 8; ++c) {
        f0 += w[c] * v[c].x;
        f1 += w[c] * v[c].y;
    }
}

__global__ __launch_bounds__(256) void ingp_hist(
    const float* __restrict__ pts, unsigned* __restrict__ hist, int npts)
{
    int i = blockIdx.x * 256 + threadIdx.x;
    if (i >= npts) return;
    float px = pts[i * 3 + 0], py = pts[i * 3 + 1], pz = pts[i * 3 + 2];
    atomicAdd(&hist[bin_key(px, py, pz)], 1u);
}

// Exclusive scan of 32768 bin counts, single block of 1024 threads.
__global__ __launch_bounds__(1024) void ingp_scan(
    const unsigned* __restrict__ hist, unsigned* __restrict__ offs)
{
    __shared__ unsigned sc[1024];
    int t = threadIdx.x;
    unsigned loc[32];
    unsigned s = 0;
    #pragma unroll
    for (int i = 0; i < 32; ++i) { loc[i] = s; s += hist[t * 32 + i]; }
    sc[t] = s;
    __syncthreads();
    for (int d = 1; d < 1024; d <<= 1) {
        unsigned v = (t >= d) ? sc[t - d] : 0u;
        __syncthreads();
        sc[t] += v;
        __syncthreads();
    }
    unsigned base = sc[t] - s;   // exclusive prefix of this thread's chunk
    #pragma unroll
    for (int i = 0; i < 32; ++i) offs[t * 32 + i] = base + loc[i];
}

// Packed scatter: one aligned 16B store per point {x,y,z,bits(orig idx)}.
__global__ __launch_bounds__(256) void ingp_scatter(
    const float* __restrict__ pts, unsigned* __restrict__ offs,
    vf4* __restrict__ pts4, int npts)
{
    int i = blockIdx.x * 256 + threadIdx.x;
    if (i >= npts) return;
    float px = pts[i * 3 + 0], py = pts[i * 3 + 1], pz = pts[i * 3 + 2];
    unsigned pos = atomicAdd(&offs[bin_key(px, py, pz)], 1u);
    vf4 o; o.x = px; o.y = py; o.z = pz; o.w = __int_as_float(i);
    pts4[pos] = o;
}

// A: fine levels 8-15, level-major, XCD-pinned; ws[lvl-8][N] coalesced.
__global__ __launch_bounds__(256) void ingp_fine(
    const vf4* __restrict__ pts4,
    const float* __restrict__ tables,
    float2* __restrict__ ws,          // [8][N] float2
    ResArr ra, int npts)
{
    int b = blockIdx.x;
    int lvl = 8 + (b & 7);            // XCD-pinned: blockIdx%8 -> XCD
    int q = b >> 3;
    int t = threadIdx.x;

    float r = ra.r[lvl];
    const float2* __restrict__ tab = (const float2*)tables + (size_t)lvl * TBL;
    float2* __restrict__ wrow = ws + (size_t)(lvl - 8) * npts;

    #pragma unroll
    for (int s = 0; s < 2; ++s) {
        int p = q * PTS_PER_BLOCK + t + s * 256;
        bool valid = p < npts;
        int pp = valid ? p : 0;
        vf4 v = pts4[pp];
        float x = (v.x + 1.0f) * 0.5f;
        float y = (v.y + 1.0f) * 0.5f;
        float z = (v.z + 1.0f) * 0.5f;
        float f0, f1;
        level_gather(tab, r, x, y, z, f0, f1);
        if (valid) {
            vf2 o; o.x = f0; o.y = f1;
            __builtin_nontemporal_store(o, (vf2*)(wrow + p));
        }
    }
}

// B: coarse levels 0-7 in registers (sorted locality) + fine rows from ws;
// assemble in LDS; write full 128B single-owner rows at original index
// via 8-lanes-per-row full-line stores.
__global__ __launch_bounds__(256) void ingp_finish(
    const vf4* __restrict__ pts4,
    const float* __restrict__ tables,
    const float2* __restrict__ ws,    // [8][N] float2
    vf4* __restrict__ out,            // [N][8] vf4 rows (original order)
    ResArr ra, int npts)
{
    __shared__ float2 a[LVLS][258];
    __shared__ int s_orig[256];
    int base = blockIdx.x * 256;
    int t = threadIdx.x;
    int p = base + t;
    bool valid = p < npts;
    int pp = valid ? p : 0;

    vf4 v4 = pts4[pp];
    s_orig[t] = __float_as_int(v4.w);
    float x = (v4.x + 1.0f) * 0.5f;
    float y = (v4.y + 1.0f) * 0.5f;
    float z = (v4.z + 1.0f) * 0.5f;

    #pragma unroll
    for (int l = 0; l < 8; ++l) {
        const float2* __restrict__ tab = (const float2*)tables + (size_t)l * TBL;
        float f0, f1;
        level_gather(tab, ra.r[l], x, y, z, f0, f1);
        a[l][t] = make_float2(f0, f1);
    }
    #pragma unroll
    for (int l = 8; l < LVLS; ++l) {
        vf2 w = __builtin_nontemporal_load(
            (const vf2*)(ws + (size_t)(l - 8) * npts + pp));
        a[l][t] = make_float2(w.x, w.y);
    }
    __syncthreads();

    int j = t & 7;
    int pl = t >> 3;
    #pragma unroll
    for (int it = 0; it < 8; ++it) {
        int pt = pl + it * 32;
        if (base + pt < npts) {
            int orig = s_orig[pt];
            float2 u = a[2 * j][pt];
            float2 v = a[2 * j + 1][pt];
            vf4 o; o.x = u.x; o.y = u.y; o.z = v.x; o.w = v.y;
            // 8 consecutive lanes cover one 128B row -> full-line stores.
            __builtin_nontemporal_store(o, (vf4*)(out + (size_t)orig * 8 + j));
        }
    }
}

// Fallback (no usable ws): R11's unsorted single-kernel path.
__global__ __launch_bounds__(256) void ingp_fused_raw(
    const float* __restrict__ pts,
    const float* __restrict__ tables,
    vf4* __restrict__ out, ResArr ra, int npts)
{
    int i = blockIdx.x * 256 + threadIdx.x;
    bool valid = i < npts;
    int pp = valid ? i : 0;
    float x = (pts[pp * 3 + 0] + 1.0f) * 0.5f;
    float y = (pts[pp * 3 + 1] + 1.0f) * 0.5f;
    float z = (pts[pp * 3 + 2] + 1.0f) * 0.5f;

    float acc[2 * LVLS];
    #pragma unroll
    for (int l = 0; l < LVLS; ++l) {
        const float2* __restrict__ tab = (const float2*)tables + (size_t)l * TBL;
        float f0, f1;
        level_gather(tab, ra.r[l], x, y, z, f0, f1);
        acc[2 * l] = f0; acc[2 * l + 1] = f1;
    }
    if (valid) {
        vf4* row = out + (size_t)pp * 8;
        #pragma unroll
        for (int k = 0; k < 8; ++k) {
            vf4 o;
            o.x = acc[4 * k + 0]; o.y = acc[4 * k + 1];
            o.z = acc[4 * k + 2]; o.w = acc[4 * k + 3];
            __builtin_nontemporal_store(o, row + k);
        }
    }
}

extern "C" void kernel_launch(void* const* d_in, const int* in_sizes, int n_in,
                              void* d_out, int out_size, void* d_ws, size_t ws_size,
                              hipStream_t stream) {
    const float* pts    = (const float*)d_in[0];
    const float* tables = (const float*)d_in[1];
    int npts = in_sizes[0] / 3;

    // numpy-bitwise RES: GROWTH = exp((log(2048)-log(16))/15); floor(16*G**l)
    ResArr ra;
    double growth = exp((log(2048.0) - log(16.0)) / 15.0);
    for (int l = 0; l < LVLS; ++l)
        ra.r[l] = (float)floor(16.0 * pow(growth, (double)l));

    int pgrid = (npts + 255) / 256;
    int bpl = (npts + PTS_PER_BLOCK - 1) / PTS_PER_BLOCK;

    // ws layout: [fine ws: 8*N float2][pts4: N vf4][hist: NBINS][offs: NBINS]
    size_t fine_bytes = 8ull * npts * sizeof(float2);
    size_t pts4_bytes = (size_t)npts * sizeof(vf4);
    size_t need = fine_bytes + pts4_bytes + 2ull * NBINS * sizeof(unsigned);

    if (ws_size >= need) {
        float2*   wsf  = (float2*)d_ws;
        vf4*      pts4 = (vf4*)((char*)d_ws + fine_bytes);
        unsigned* hist = (unsigned*)((char*)d_ws + fine_bytes + pts4_bytes);
        unsigned* offs = hist + NBINS;

        hipMemsetAsync(hist, 0, NBINS * sizeof(unsigned), stream);
        hipLaunchKernelGGL(ingp_hist, dim3(pgrid), dim3(256), 0, stream,
                           pts, hist, npts);
        hipLaunchKernelGGL(ingp_scan, dim3(1), dim3(1024), 0, stream,
                           hist, offs);
        hipLaunchKernelGGL(ingp_scatter, dim3(pgrid), dim3(256), 0, stream,
                           pts, offs, pts4, npts);
        hipLaunchKernelGGL(ingp_fine, dim3(8 * bpl), dim3(256), 0, stream,
                           pts4, tables, wsf, ra, npts);
        hipLaunchKernelGGL(ingp_finish, dim3(pgrid), dim3(256), 0, stream,
                           pts4, tables, wsf, (vf4*)d_out, ra, npts);
    } else {
        hipLaunchKernelGGL(ingp_fused_raw, dim3(pgrid), dim3(256), 0, stream,
                           pts, tables, (vf4*)d_out, ra, npts);
    }
}